// Round 18
// baseline (134.599 us; speedup 1.0000x reference)
//
#include <hip/hip_runtime.h>
#include <math.h>

#define NN 20000
#define NE 640000
#define HID 128
#define NH 8
#define HD 16
#define ATT_SCALE 0.25f

// counting-sort geometry (R9-proven)
#define EPB 4096                 // edges per pass-1 block
#define NBLK1 157                // ceil(NE/EPB)
#define NBUCK 157                // ceil(NN/128), bucket = dst>>7 (128 nodes)
#define SCAN_N (NBUCK * NBLK1)   // 24649
#define SPT 25                   // 1024*25 = 25600 >= SCAN_N
#define PCHUNK 79                // proj blocks per matrix: ceil(NN/256)

typedef __attribute__((ext_vector_type(8))) short bhalf8;
typedef __attribute__((ext_vector_type(4))) float floatx4;

// ============================ bf16 helpers ============================
__device__ __forceinline__ short f2b(float f) {  // RNE f32->bf16
  union { float f; unsigned u; } a;
  a.f = f;
  unsigned r = a.u + 0x7FFF + ((a.u >> 16) & 1);
  return (short)(r >> 16);
}

__device__ __forceinline__ float b2f(short s) {
  union { unsigned u; float f; } a;
  a.u = ((unsigned)(unsigned short)s) << 16;
  return a.f;
}

__device__ __forceinline__ bhalf8 load_a8(const float* __restrict__ p) {
  float4 x0 = *(const float4*)p;
  float4 x1 = *(const float4*)(p + 4);
  bhalf8 a;
  a[0] = f2b(x0.x); a[1] = f2b(x0.y); a[2] = f2b(x0.z); a[3] = f2b(x0.w);
  a[4] = f2b(x1.x); a[5] = f2b(x1.y); a[6] = f2b(x1.z); a[7] = f2b(x1.w);
  return a;
}

// ============================ fused: coarse histogram + weight convert ============================
__global__ __launch_bounds__(256) void k_hist_wconv(
    const int* __restrict__ dst, int* __restrict__ cnt1,
    const float* __restrict__ W0, const float* __restrict__ W1,
    const float* __restrict__ W2, const float* __restrict__ W3,
    short* __restrict__ out) {
  int t = threadIdx.x, b = blockIdx.x;
  if (b < NBLK1) {
    __shared__ int h[NBUCK];
    for (int i = t; i < NBUCK; i += 256) h[i] = 0;
    __syncthreads();
    int e0 = b * EPB;
#pragma unroll
    for (int it = 0; it < EPB / 256; ++it) {
      int e = e0 + it * 256 + t;
      if (e < NE) atomicAdd(&h[dst[e] >> 7], 1);
    }
    __syncthreads();
    for (int i = t; i < NBUCK; i += 256) cnt1[i * NBLK1 + b] = h[i];
  } else {
    int i = (b - NBLK1) * 1024 + t * 4;  // 64*1024 = 65536 total
    int m = i >> 14;
    const float* src = (m == 0) ? W0 : (m == 1) ? W1 : (m == 2) ? W2 : W3;
    float4 x = *(const float4*)(src + (i & 16383));
    short4 o;
    o.x = f2b(x.x); o.y = f2b(x.y); o.z = f2b(x.z); o.w = f2b(x.w);
    *(short4*)(out + i) = o;
  }
}

// ============================ 1-block scan (bucket-major exclusive prefix) ============================
__global__ __launch_bounds__(1024) void k_scan(int* __restrict__ cnt1,
                                               int* __restrict__ boff) {
  __shared__ int sa[1024], sb[1024];
  int t = threadIdx.x;
  int base = t * SPT;
  int s = 0;
#pragma unroll 5
  for (int u = 0; u < SPT; ++u) {
    int i = base + u;
    s += (i < SCAN_N) ? cnt1[i] : 0;
  }
  sa[t] = s;
  __syncthreads();
  int* sp = sa;
  int* dp = sb;
  for (int st = 1; st < 1024; st <<= 1) {
    dp[t] = sp[t] + (t >= st ? sp[t - st] : 0);
    __syncthreads();
    int* tmp = sp; sp = dp; dp = tmp;
  }
  int run = sp[t] - s;
#pragma unroll 5
  for (int u = 0; u < SPT; ++u) {
    int i = base + u;
    if (i < SCAN_N) {
      int vv = cnt1[i];
      cnt1[i] = run;
      run += vv;
    }
  }
  __syncthreads();
  for (int i = t; i < NBUCK; i += 1024) boff[i] = cnt1[i * NBLK1];
  if (t == 0) boff[NBUCK] = NE;
}

// ============================ MFMA GEMM (projections) ============================
// bf16 head-pair layout out[((nt>>1)*NN + r)*STRIDE + HALF + (nt&1)*16 + rr]
//   Q: STRIDE=32 HALF=0;  K: STRIDE=64 HALF=0;  V: STRIDE=64 HALF=32 (K|V packed).
template <int STRIDE, int HALF>
__device__ __forceinline__ void gemm_mfma(const float* __restrict__ X,
                                          const short* __restrict__ Wb,
                                          const float* __restrict__ B,
                                          short* __restrict__ O, int wrow) {
  int lane = threadIdx.x & 63;
  int rr = lane & 15;
  int g = lane >> 4;
  int arow = wrow + rr;
  floatx4 acc[8];
#pragma unroll
  for (int nt = 0; nt < 8; ++nt) acc[nt] = (floatx4){0.f, 0.f, 0.f, 0.f};
#pragma unroll
  for (int kt = 0; kt < 4; ++kt) {
    bhalf8 a;
    if (arow < NN) {
      a = load_a8(X + (size_t)arow * HID + kt * 32 + g * 8);
    } else {
      a = (bhalf8){0, 0, 0, 0, 0, 0, 0, 0};
    }
#pragma unroll
    for (int nt = 0; nt < 8; ++nt) {
      bhalf8 b = *(const bhalf8*)(Wb + (nt * 16 + rr) * HID + kt * 32 + g * 8);
      acc[nt] = __builtin_amdgcn_mfma_f32_16x16x32_bf16(a, b, acc[nt], 0, 0, 0);
    }
  }
  int orow0 = wrow + g * 4;
#pragma unroll
  for (int nt = 0; nt < 8; ++nt) {
    int col = nt * 16 + rr;
    float bias = B[col];
#pragma unroll
    for (int i = 0; i < 4; ++i) {
      int r = orow0 + i;
      if (r < NN) {
        O[((size_t)(nt >> 1) * NN + r) * STRIDE + HALF + (nt & 1) * 16 + rr] =
            f2b(acc[nt][i] + bias);
      }
    }
  }
}

// ============================ fused: projections + p1scat ============================
// blocks [0, 3*PCHUNK): Q/K/V projection (16 waves x 16 rows).
// blocks [3*PCHUNK, +NBLK1): scatter packed (src<<7 | dst&127) into
// bucket-major tmp via LDS cursors (1024 threads, 4 edges each) — p1scat
// hidden under the projection GEMMs (both only depend on hist/scan/wconv).
__global__ __launch_bounds__(1024) void k_proj_scat(
    const int* __restrict__ cnt1, int* __restrict__ tmp,
    const int* __restrict__ esrc, const int* __restrict__ edst,
    const float* __restrict__ q, const float* __restrict__ k,
    const float* __restrict__ v, const short* __restrict__ Wb,
    const float* __restrict__ bq, const float* __restrict__ bk,
    const float* __restrict__ bv, short* __restrict__ Qh,
    short* __restrict__ KVh) {
  int b = blockIdx.x;
  int t = threadIdx.x;
  if (b < 3 * PCHUNK) {
    int mat = b / PCHUNK;
    int wrow = (b % PCHUNK) * 256 + (t >> 6) * 16;
    if (mat == 0) gemm_mfma<32, 0>(q, Wb, bq, Qh, wrow);
    else if (mat == 1) gemm_mfma<64, 0>(k, Wb + 16384, bk, KVh, wrow);
    else gemm_mfma<64, 32>(v, Wb + 2 * 16384, bv, KVh, wrow);
  } else {
    int sb = b - 3 * PCHUNK;  // 0..NBLK1-1
    __shared__ int cur[NBUCK];
    if (t < NBUCK) cur[t] = cnt1[t * NBLK1 + sb];
    __syncthreads();
    int e0 = sb * EPB;
#pragma unroll
    for (int it = 0; it < EPB / 1024; ++it) {
      int e = e0 + it * 1024 + t;
      if (e < NE) {
        int d = edst[e];
        int p = atomicAdd(&cur[d >> 7], 1);  // LDS atomic
        tmp[p] = (esrc[e] << 7) | (d & 127);
      }
    }
  }
}

// ============================ fused edge attention (p2-inline + attn + out-GEMM) ============================
// Grid = NBUCK*16 = 2512 blocks, 128 threads (2 waves) — proven FETCH-optimal
// L2-phasing configuration. Block bx owns nodes [8*bx, 8*bx+8).
// Phase 1 (R15-identical): int4-stream bucket's tmp range -> block CSR in LDS.
// Phase 2 (R17 4-lane/edge + 4-edge unroll): lane sub = j*4 + r; j = edge
//   slot, r = chunk role (head hq = r>>1). Lane r loads K-chunk r and V-chunk
//   r: 4 lanes cover each 64 B K/V line exactly. Zero waste: after
//   shfl_xor(1), lane r holds p of head r>>1 — exactly its V-chunk's head.
//   4-edge unroll = 8 independent 16 B loads in flight per lane (VGPR 36 had
//   headroom; halves load-wait rounds vs R17's 2-edge). NO-MAX softmax.
//   j-merge shfl_xor{4,8}; j=0's 4 r-lanes write the 32-dim hp slice.
// Phase 3 (R15-identical): out-GEMM from att[8][136] LDS.
__global__ __launch_bounds__(128, 4) void k_edge(
    const int* __restrict__ tmp, const int* __restrict__ boff,
    const short* __restrict__ Qh, const short* __restrict__ KVh,
    const short* __restrict__ Wb, const float* __restrict__ bo,
    float* __restrict__ O) {
  __shared__ int hits[512];
  __shared__ int els[512];
  __shared__ short att[8][136];   // +8 pad: 17x16B row stride, conflict-free b128
  __shared__ int h8[8], c8[8], o8[8];
  __shared__ int nhit;
  int t = threadIdx.x;
  int bx = blockIdx.x;
  int b = bx >> 4;
  int l0 = (bx & 15) * 8;
  int node0 = 8 * bx;
  if (t < 8) h8[t] = 0;
  if (t == 0) nhit = 0;
  __syncthreads();
  // ---- phase 1: int4-stream the bucket's tmp range, filter locals [l0,l0+8) ----
  int lo = boff[b], hi = boff[b + 1];
  const int4* t4 = (const int4*)tmp;  // d_ws is 16B-aligned
  int q0i = lo >> 2, q1i = (hi + 3) >> 2;
  for (int i4 = q0i + t; i4 < q1i; i4 += 128) {
    int4 w4 = t4[i4];
    int e = 4 * i4;
#pragma unroll
    for (int u = 0; u < 4; ++u) {
      int w = (u == 0) ? w4.x : (u == 1) ? w4.y : (u == 2) ? w4.z : w4.w;
      int ei = e + u;
      if (ei >= lo && ei < hi) {
        unsigned rel = (unsigned)((w & 127) - l0);
        if (rel < 8u) {
          int p = atomicAdd(&nhit, 1);
          if (p < 512) hits[p] = w;
          atomicAdd(&h8[rel], 1);
        }
      }
    }
  }
  __syncthreads();
  if (t == 0) {
    int r = 0;
#pragma unroll
    for (int u = 0; u < 8; ++u) {
      o8[u] = r;
      c8[u] = r;
      r += h8[u];
    }
  }
  __syncthreads();
  int n = nhit < 512 ? nhit : 512;
  for (int i = t; i < n; i += 128) {
    int w = hits[i];
    int p = atomicAdd(&c8[(w & 127) - l0], 1);  // LDS atomic
    els[p] = w >> 7;
  }
  __syncthreads();
  // ---- phase 2: attention, 4-lanes-per-edge, 4-edge unroll ----
  int nl = t >> 4;              // local node 0..7
  int node = node0 + nl;
  int sub = t & 15;
  int j = sub >> 2;             // edge slot 0..3
  int r = sub & 3;              // chunk role: head hq = r>>1, half r&1
  int i0 = o8[nl];
  int i1 = i0 + h8[nl];
  bool valid = node < NN;
#pragma unroll
  for (int hp = 0; hp < 4; ++hp) {
    float qf[8];
    if (valid) {
      bhalf8 qv = *(const bhalf8*)(Qh + ((size_t)hp * NN + node) * 32 + r * 8);
#pragma unroll
      for (int u = 0; u < 8; ++u) qf[u] = b2f(qv[u]);
    } else {
#pragma unroll
      for (int u = 0; u < 8; ++u) qf[u] = 0.f;
    }
    float l = 0.f;
    float acc[8];
#pragma unroll
    for (int u = 0; u < 8; ++u) acc[u] = 0.f;
    int i = i0 + j;
    for (; i + 12 < i1; i += 16) {  // FOUR edges: 8 independent loads in flight
      int s1 = els[i], s2 = els[i + 4], s3 = els[i + 8], s4 = els[i + 12];
      const short* b1 = KVh + ((size_t)hp * NN + s1) * 64;
      const short* b2 = KVh + ((size_t)hp * NN + s2) * 64;
      const short* b3 = KVh + ((size_t)hp * NN + s3) * 64;
      const short* b4 = KVh + ((size_t)hp * NN + s4) * 64;
      bhalf8 kc1 = *(const bhalf8*)(b1 + r * 8);
      bhalf8 vc1 = *(const bhalf8*)(b1 + 32 + r * 8);
      bhalf8 kc2 = *(const bhalf8*)(b2 + r * 8);
      bhalf8 vc2 = *(const bhalf8*)(b2 + 32 + r * 8);
      bhalf8 kc3 = *(const bhalf8*)(b3 + r * 8);
      bhalf8 vc3 = *(const bhalf8*)(b3 + 32 + r * 8);
      bhalf8 kc4 = *(const bhalf8*)(b4 + r * 8);
      bhalf8 vc4 = *(const bhalf8*)(b4 + 32 + r * 8);
      float d1 = 0.f, d2 = 0.f, d3 = 0.f, d4 = 0.f;
#pragma unroll
      for (int u = 0; u < 8; ++u) {
        d1 += qf[u] * b2f(kc1[u]);
        d2 += qf[u] * b2f(kc2[u]);
        d3 += qf[u] * b2f(kc3[u]);
        d4 += qf[u] * b2f(kc4[u]);
      }
      d1 += __shfl_xor(d1, 1, 64);  // pair-sum within head: full 16-dim dot
      d2 += __shfl_xor(d2, 1, 64);
      d3 += __shfl_xor(d3, 1, 64);
      d4 += __shfl_xor(d4, 1, 64);
      float p1 = __expf(d1 * ATT_SCALE);
      float p2 = __expf(d2 * ATT_SCALE);
      float p3 = __expf(d3 * ATT_SCALE);
      float p4 = __expf(d4 * ATT_SCALE);
      l += (p1 + p2) + (p3 + p4);   // lane counts its own head only
#pragma unroll
      for (int u = 0; u < 8; ++u)
        acc[u] += p1 * b2f(vc1[u]) + p2 * b2f(vc2[u]) + p3 * b2f(vc3[u]) +
                  p4 * b2f(vc4[u]);
    }
    for (; i + 4 < i1; i += 8) {  // two edges
      int s1 = els[i], s2 = els[i + 4];
      const short* b1 = KVh + ((size_t)hp * NN + s1) * 64;
      const short* b2 = KVh + ((size_t)hp * NN + s2) * 64;
      bhalf8 kc1 = *(const bhalf8*)(b1 + r * 8);
      bhalf8 vc1 = *(const bhalf8*)(b1 + 32 + r * 8);
      bhalf8 kc2 = *(const bhalf8*)(b2 + r * 8);
      bhalf8 vc2 = *(const bhalf8*)(b2 + 32 + r * 8);
      float d1 = 0.f, d2 = 0.f;
#pragma unroll
      for (int u = 0; u < 8; ++u) {
        d1 += qf[u] * b2f(kc1[u]);
        d2 += qf[u] * b2f(kc2[u]);
      }
      d1 += __shfl_xor(d1, 1, 64);
      d2 += __shfl_xor(d2, 1, 64);
      float p1 = __expf(d1 * ATT_SCALE);
      float p2 = __expf(d2 * ATT_SCALE);
      l += p1 + p2;
#pragma unroll
      for (int u = 0; u < 8; ++u) acc[u] += p1 * b2f(vc1[u]) + p2 * b2f(vc2[u]);
    }
    if (i < i1) {  // tail edge
      int s1 = els[i];
      const short* b1 = KVh + ((size_t)hp * NN + s1) * 64;
      bhalf8 kc1 = *(const bhalf8*)(b1 + r * 8);
      bhalf8 vc1 = *(const bhalf8*)(b1 + 32 + r * 8);
      float d1 = 0.f;
#pragma unroll
      for (int u = 0; u < 8; ++u) d1 += qf[u] * b2f(kc1[u]);
      d1 += __shfl_xor(d1, 1, 64);
      float p1 = __expf(d1 * ATT_SCALE);
      l += p1;
#pragma unroll
      for (int u = 0; u < 8; ++u) acc[u] += p1 * b2f(vc1[u]);
    }
    // merge the 4 edge slots (lane bits 2..3)
#pragma unroll
    for (int mask = 4; mask <= 8; mask <<= 1) {
      l += __shfl_xor(l, mask, 64);
#pragma unroll
      for (int u = 0; u < 8; ++u) acc[u] += __shfl_xor(acc[u], mask, 64);
    }
    float inv = 1.f / (l + 1e-8f);  // degree 0 -> acc 0 -> out 0 (matches ref)
    if (j == 0) {  // 4 r-lanes write 8 dims each = full 32-dim hp slice
      bhalf8 st;
#pragma unroll
      for (int u = 0; u < 8; ++u) st[u] = f2b(acc[u] * inv);
      *(bhalf8*)(&att[nl][hp * 32 + r * 8]) = st;
    }
  }
  __syncthreads();
  // ---- phase 3: out-projection of this block's 8 rows (O = att @ Wo^T + bo) ----
  int w = t >> 6;               // wave 0: cols 0..63, wave 1: cols 64..127
  int plane = t & 63;
  int rr = plane & 15;
  int pg = plane >> 4;
  const short* Wo = Wb + 3 * 16384;
  floatx4 oacc[4];
#pragma unroll
  for (int ntl = 0; ntl < 4; ++ntl) oacc[ntl] = (floatx4){0.f, 0.f, 0.f, 0.f};
#pragma unroll
  for (int kt = 0; kt < 4; ++kt) {
    bhalf8 a;
    if (rr < 8 && node0 + rr < NN) {
      a = *(const bhalf8*)(&att[rr][kt * 32 + pg * 8]);
    } else {
      a = (bhalf8){0, 0, 0, 0, 0, 0, 0, 0};
    }
#pragma unroll
    for (int ntl = 0; ntl < 4; ++ntl) {
      int nt = w * 4 + ntl;
      bhalf8 bb = *(const bhalf8*)(Wo + (nt * 16 + rr) * HID + kt * 32 + pg * 8);
      oacc[ntl] = __builtin_amdgcn_mfma_f32_16x16x32_bf16(a, bb, oacc[ntl], 0, 0, 0);
    }
  }
#pragma unroll
  for (int ntl = 0; ntl < 4; ++ntl) {
    int col = (w * 4 + ntl) * 16 + rr;
    float bias = bo[col];
#pragma unroll
    for (int ii = 0; ii < 4; ++ii) {
      int rw = pg * 4 + ii;  // row in 16-row tile; valid rows are 0..7
      if (rw < 8 && node0 + rw < NN) {
        O[(size_t)(node0 + rw) * HID + col] = oacc[ntl][ii] + bias;
      }
    }
  }
}

// ============================ launch ============================
extern "C" void kernel_launch(void* const* d_in, const int* in_sizes, int n_in,
                              void* d_out, int out_size, void* d_ws,
                              size_t ws_size, hipStream_t stream) {
  const float* q = (const float*)d_in[0];
  const float* k = (const float*)d_in[1];
  const float* v = (const float*)d_in[2];
  const int* ei = (const int*)d_in[3];
  const float* Wq = (const float*)d_in[4];
  const float* bq = (const float*)d_in[5];
  const float* Wk = (const float*)d_in[6];
  const float* bk = (const float*)d_in[7];
  const float* Wv = (const float*)d_in[8];
  const float* bv = (const float*)d_in[9];
  const float* Wo = (const float*)d_in[10];
  const float* bo = (const float*)d_in[11];
  const int* src = ei;
  const int* dst = ei + NE;

  // workspace layout (16B-aligned sections)
  int* tmp = (int*)d_ws;                    // NE ints (packed src<<7|bin)
  int* cnt1 = tmp + NE;                     // 24704
  int* boff = cnt1 + 24704;                 // 160
  short* Wb = (short*)(boff + 160);         // 4*16384 bf16
  short* Qh = Wb + 4 * 16384;               // [4][NN][32] bf16
  short* KVh = Qh + NN * HID;               // [4][NN][64] bf16 (K|V packed)
  float* O = (float*)d_out;

  k_hist_wconv<<<NBLK1 + 64, 256, 0, stream>>>(dst, cnt1, Wq, Wk, Wv, Wo, Wb);
  k_scan<<<1, 1024, 0, stream>>>(cnt1, boff);
  k_proj_scat<<<3 * PCHUNK + NBLK1, 1024, 0, stream>>>(
      cnt1, tmp, src, dst, q, k, v, Wb, bq, bk, bv, Qh, KVh);
  k_edge<<<NBUCK * 16, 128, 0, stream>>>(tmp, boff, Qh, KVh, Wb, bo, O);
}

// Round 19
// 98.230 us; speedup vs baseline: 1.3702x; 1.3702x over previous
//
#include <hip/hip_runtime.h>
#include <math.h>

#define NN 20000
#define NE 640000
#define HID 128
#define NH 8
#define HD 16
#define ATT_SCALE 0.25f

// counting-sort geometry (R9-proven)
#define EPB 4096                 // edges per pass-1 block
#define NBLK1 157                // ceil(NE/EPB)
#define NBUCK 157                // ceil(NN/128), bucket = dst>>7 (128 nodes)
#define SCAN_N (NBUCK * NBLK1)   // 24649
#define SPT 25                   // 1024*25 = 25600 >= SCAN_N
#define PCHUNK 79                // proj blocks per matrix: ceil(NN/256)

typedef __attribute__((ext_vector_type(8))) short bhalf8;
typedef __attribute__((ext_vector_type(4))) float floatx4;

// ============================ bf16 helpers ============================
__device__ __forceinline__ short f2b(float f) {  // RNE f32->bf16
  union { float f; unsigned u; } a;
  a.f = f;
  unsigned r = a.u + 0x7FFF + ((a.u >> 16) & 1);
  return (short)(r >> 16);
}

__device__ __forceinline__ float b2f(short s) {
  union { unsigned u; float f; } a;
  a.u = ((unsigned)(unsigned short)s) << 16;
  return a.f;
}

__device__ __forceinline__ bhalf8 load_a8(const float* __restrict__ p) {
  float4 x0 = *(const float4*)p;
  float4 x1 = *(const float4*)(p + 4);
  bhalf8 a;
  a[0] = f2b(x0.x); a[1] = f2b(x0.y); a[2] = f2b(x0.z); a[3] = f2b(x0.w);
  a[4] = f2b(x1.x); a[5] = f2b(x1.y); a[6] = f2b(x1.z); a[7] = f2b(x1.w);
  return a;
}

// ============================ fused: coarse histogram + weight convert ============================
// hist blocks stream dst as int4 (4 edges/thread/load, 4 rounds vs 16 scalar).
__global__ __launch_bounds__(256) void k_hist_wconv(
    const int* __restrict__ dst, int* __restrict__ cnt1,
    const float* __restrict__ W0, const float* __restrict__ W1,
    const float* __restrict__ W2, const float* __restrict__ W3,
    short* __restrict__ out) {
  int t = threadIdx.x, b = blockIdx.x;
  if (b < NBLK1) {
    __shared__ int h[NBUCK];
    for (int i = t; i < NBUCK; i += 256) h[i] = 0;
    __syncthreads();
    const int4* d4 = (const int4*)dst;  // NE % 4 == 0
    int q0 = (b * EPB) >> 2;            // EPB % 4 == 0
#pragma unroll
    for (int it = 0; it < EPB / 1024; ++it) {
      int i4 = q0 + it * 256 + t;
      if (i4 < NE / 4) {
        int4 d = d4[i4];
        atomicAdd(&h[d.x >> 7], 1);
        atomicAdd(&h[d.y >> 7], 1);
        atomicAdd(&h[d.z >> 7], 1);
        atomicAdd(&h[d.w >> 7], 1);
      }
    }
    __syncthreads();
    for (int i = t; i < NBUCK; i += 256) cnt1[i * NBLK1 + b] = h[i];
  } else {
    int i = (b - NBLK1) * 1024 + t * 4;  // 64*1024 = 65536 total
    int m = i >> 14;
    const float* src = (m == 0) ? W0 : (m == 1) ? W1 : (m == 2) ? W2 : W3;
    float4 x = *(const float4*)(src + (i & 16383));
    short4 o;
    o.x = f2b(x.x); o.y = f2b(x.y); o.z = f2b(x.z); o.w = f2b(x.w);
    *(short4*)(out + i) = o;
  }
}

// ============================ MFMA GEMM (projections) ============================
// bf16 head-pair layout out[((nt>>1)*NN + r)*STRIDE + HALF + (nt&1)*16 + rr]
//   Q: STRIDE=32 HALF=0;  K: STRIDE=64 HALF=0;  V: STRIDE=64 HALF=32 (K|V packed).
template <int STRIDE, int HALF>
__device__ __forceinline__ void gemm_mfma(const float* __restrict__ X,
                                          const short* __restrict__ Wb,
                                          const float* __restrict__ B,
                                          short* __restrict__ O, int wrow) {
  int lane = threadIdx.x & 63;
  int rr = lane & 15;
  int g = lane >> 4;
  int arow = wrow + rr;
  floatx4 acc[8];
#pragma unroll
  for (int nt = 0; nt < 8; ++nt) acc[nt] = (floatx4){0.f, 0.f, 0.f, 0.f};
#pragma unroll
  for (int kt = 0; kt < 4; ++kt) {
    bhalf8 a;
    if (arow < NN) {
      a = load_a8(X + (size_t)arow * HID + kt * 32 + g * 8);
    } else {
      a = (bhalf8){0, 0, 0, 0, 0, 0, 0, 0};
    }
#pragma unroll
    for (int nt = 0; nt < 8; ++nt) {
      bhalf8 b = *(const bhalf8*)(Wb + (nt * 16 + rr) * HID + kt * 32 + g * 8);
      acc[nt] = __builtin_amdgcn_mfma_f32_16x16x32_bf16(a, b, acc[nt], 0, 0, 0);
    }
  }
  int orow0 = wrow + g * 4;
#pragma unroll
  for (int nt = 0; nt < 8; ++nt) {
    int col = nt * 16 + rr;
    float bias = B[col];
#pragma unroll
    for (int i = 0; i < 4; ++i) {
      int r = orow0 + i;
      if (r < NN) {
        O[((size_t)(nt >> 1) * NN + r) * STRIDE + HALF + (nt & 1) * 16 + rr] =
            f2b(acc[nt][i] + bias);
      }
    }
  }
}

// ============================ fused: 1-block scan + projections ============================
__global__ __launch_bounds__(1024) void k_scan_proj(
    int* __restrict__ cnt1, int* __restrict__ boff,
    const float* __restrict__ q, const float* __restrict__ k,
    const float* __restrict__ v, const short* __restrict__ Wb,
    const float* __restrict__ bq, const float* __restrict__ bk,
    const float* __restrict__ bv, short* __restrict__ Qh,
    short* __restrict__ KVh) {
  __shared__ int sa[1024], sb[1024];
  int t = threadIdx.x;
  if (blockIdx.x == 0) {
    int base = t * SPT;
    int s = 0;
#pragma unroll 5
    for (int u = 0; u < SPT; ++u) {
      int i = base + u;
      s += (i < SCAN_N) ? cnt1[i] : 0;
    }
    sa[t] = s;
    __syncthreads();
    int* sp = sa;
    int* dp = sb;
    for (int st = 1; st < 1024; st <<= 1) {
      dp[t] = sp[t] + (t >= st ? sp[t - st] : 0);
      __syncthreads();
      int* tmp = sp; sp = dp; dp = tmp;
    }
    int run = sp[t] - s;
#pragma unroll 5
    for (int u = 0; u < SPT; ++u) {
      int i = base + u;
      if (i < SCAN_N) {
        int vv = cnt1[i];
        cnt1[i] = run;
        run += vv;
      }
    }
    __syncthreads();
    for (int i = t; i < NBUCK; i += 1024) boff[i] = cnt1[i * NBLK1];
    if (t == 0) boff[NBUCK] = NE;
  } else {
    int b = blockIdx.x - 1;
    int mat = b / PCHUNK;
    int wrow = (b % PCHUNK) * 256 + (t >> 6) * 16;
    if (mat == 0) gemm_mfma<32, 0>(q, Wb, bq, Qh, wrow);
    else if (mat == 1) gemm_mfma<64, 0>(k, Wb + 16384, bk, KVh, wrow);
    else gemm_mfma<64, 32>(v, Wb + 2 * 16384, bv, KVh, wrow);
  }
}

// p1c: scatter packed (src<<7 | dst&127) into bucket-major tmp (LDS cursors).
// src/dst streamed as int4: 4 edges/thread/load, 4 rounds vs 16 scalar.
__global__ __launch_bounds__(256) void k_p1scat(const int* __restrict__ src,
                                                const int* __restrict__ dst,
                                                const int* __restrict__ cnt1,
                                                int* __restrict__ tmp) {
  __shared__ int cur[NBUCK];
  int t = threadIdx.x, b = blockIdx.x;
  for (int i = t; i < NBUCK; i += 256) cur[i] = cnt1[i * NBLK1 + b];
  __syncthreads();
  const int4* s4 = (const int4*)src;  // NE % 4 == 0
  const int4* d4 = (const int4*)dst;
  int q0 = (b * EPB) >> 2;
#pragma unroll
  for (int it = 0; it < EPB / 1024; ++it) {
    int i4 = q0 + it * 256 + t;
    if (i4 < NE / 4) {
      int4 s = s4[i4];
      int4 d = d4[i4];
      int p;
      p = atomicAdd(&cur[d.x >> 7], 1); tmp[p] = (s.x << 7) | (d.x & 127);
      p = atomicAdd(&cur[d.y >> 7], 1); tmp[p] = (s.y << 7) | (d.y & 127);
      p = atomicAdd(&cur[d.z >> 7], 1); tmp[p] = (s.z << 7) | (d.z & 127);
      p = atomicAdd(&cur[d.w >> 7], 1); tmp[p] = (s.w << 7) | (d.w & 127);
    }
  }
}

// ============================ fused edge attention (p2-inline + attn + out-GEMM) ============================
// R17-proven (52.4 us): grid = NBUCK*16 = 2512 blocks, 128 threads (2 waves).
// Block bx owns nodes [8*bx, 8*bx+8).
// Phase 1: int4-stream bucket's tmp range -> block CSR in LDS.
// Phase 2 (4-lane/edge, 2-edge unroll — R18's 4-edge unroll REGRESSED
//   52->82 us via VGPR 36->52 + occupancy drop; do not deepen): lane
//   sub = j*4 + r; j = edge slot, r = chunk role (head hq = r>>1). Lane r
//   loads K-chunk r and V-chunk r: 4 lanes cover each 64 B K/V line exactly.
//   Zero waste: after shfl_xor(1), lane r holds p of head r>>1 — exactly its
//   V-chunk's head. NO-MAX softmax. j-merge shfl_xor{4,8}; j=0's r-lanes
//   write the 32-dim hp slice.
// Phase 3: out-GEMM from att[8][136] LDS.
__global__ __launch_bounds__(128, 4) void k_edge(
    const int* __restrict__ tmp, const int* __restrict__ boff,
    const short* __restrict__ Qh, const short* __restrict__ KVh,
    const short* __restrict__ Wb, const float* __restrict__ bo,
    float* __restrict__ O) {
  __shared__ int hits[512];
  __shared__ int els[512];
  __shared__ short att[8][136];   // +8 pad: 17x16B row stride, conflict-free b128
  __shared__ int h8[8], c8[8], o8[8];
  __shared__ int nhit;
  int t = threadIdx.x;
  int bx = blockIdx.x;
  int b = bx >> 4;
  int l0 = (bx & 15) * 8;
  int node0 = 8 * bx;
  if (t < 8) h8[t] = 0;
  if (t == 0) nhit = 0;
  __syncthreads();
  // ---- phase 1: int4-stream the bucket's tmp range, filter locals [l0,l0+8) ----
  int lo = boff[b], hi = boff[b + 1];
  const int4* t4 = (const int4*)tmp;  // d_ws is 16B-aligned
  int q0i = lo >> 2, q1i = (hi + 3) >> 2;
  for (int i4 = q0i + t; i4 < q1i; i4 += 128) {
    int4 w4 = t4[i4];
    int e = 4 * i4;
#pragma unroll
    for (int u = 0; u < 4; ++u) {
      int w = (u == 0) ? w4.x : (u == 1) ? w4.y : (u == 2) ? w4.z : w4.w;
      int ei = e + u;
      if (ei >= lo && ei < hi) {
        unsigned rel = (unsigned)((w & 127) - l0);
        if (rel < 8u) {
          int p = atomicAdd(&nhit, 1);
          if (p < 512) hits[p] = w;
          atomicAdd(&h8[rel], 1);
        }
      }
    }
  }
  __syncthreads();
  if (t == 0) {
    int r = 0;
#pragma unroll
    for (int u = 0; u < 8; ++u) {
      o8[u] = r;
      c8[u] = r;
      r += h8[u];
    }
  }
  __syncthreads();
  int n = nhit < 512 ? nhit : 512;
  for (int i = t; i < n; i += 128) {
    int w = hits[i];
    int p = atomicAdd(&c8[(w & 127) - l0], 1);  // LDS atomic
    els[p] = w >> 7;
  }
  __syncthreads();
  // ---- phase 2: attention, 4-lanes-per-edge ----
  int nl = t >> 4;              // local node 0..7
  int node = node0 + nl;
  int sub = t & 15;
  int j = sub >> 2;             // edge slot 0..3
  int r = sub & 3;              // chunk role: head hq = r>>1, half r&1
  int i0 = o8[nl];
  int i1 = i0 + h8[nl];
  bool valid = node < NN;
#pragma unroll
  for (int hp = 0; hp < 4; ++hp) {
    float qf[8];
    if (valid) {
      bhalf8 qv = *(const bhalf8*)(Qh + ((size_t)hp * NN + node) * 32 + r * 8);
#pragma unroll
      for (int u = 0; u < 8; ++u) qf[u] = b2f(qv[u]);
    } else {
#pragma unroll
      for (int u = 0; u < 8; ++u) qf[u] = 0.f;
    }
    float l = 0.f;
    float acc[8];
#pragma unroll
    for (int u = 0; u < 8; ++u) acc[u] = 0.f;
    int i = i0 + j;
    for (; i + 4 < i1; i += 8) {  // two edges per iteration: 4 loads in flight
      int s1 = els[i], s2 = els[i + 4];
      const short* b1 = KVh + ((size_t)hp * NN + s1) * 64;
      const short* b2 = KVh + ((size_t)hp * NN + s2) * 64;
      bhalf8 kc1 = *(const bhalf8*)(b1 + r * 8);
      bhalf8 vc1 = *(const bhalf8*)(b1 + 32 + r * 8);
      bhalf8 kc2 = *(const bhalf8*)(b2 + r * 8);
      bhalf8 vc2 = *(const bhalf8*)(b2 + 32 + r * 8);
      float d1 = 0.f, d2 = 0.f;
#pragma unroll
      for (int u = 0; u < 8; ++u) {
        d1 += qf[u] * b2f(kc1[u]);
        d2 += qf[u] * b2f(kc2[u]);
      }
      d1 += __shfl_xor(d1, 1, 64);  // pair-sum within head: full 16-dim dot
      d2 += __shfl_xor(d2, 1, 64);
      float p1 = __expf(d1 * ATT_SCALE);
      float p2 = __expf(d2 * ATT_SCALE);
      l += p1 + p2;                 // lane counts its own head only
#pragma unroll
      for (int u = 0; u < 8; ++u) acc[u] += p1 * b2f(vc1[u]) + p2 * b2f(vc2[u]);
    }
    if (i < i1) {  // tail edge
      int s1 = els[i];
      const short* b1 = KVh + ((size_t)hp * NN + s1) * 64;
      bhalf8 kc1 = *(const bhalf8*)(b1 + r * 8);
      bhalf8 vc1 = *(const bhalf8*)(b1 + 32 + r * 8);
      float d1 = 0.f;
#pragma unroll
      for (int u = 0; u < 8; ++u) d1 += qf[u] * b2f(kc1[u]);
      d1 += __shfl_xor(d1, 1, 64);
      float p1 = __expf(d1 * ATT_SCALE);
      l += p1;
#pragma unroll
      for (int u = 0; u < 8; ++u) acc[u] += p1 * b2f(vc1[u]);
    }
    // merge the 4 edge slots (lane bits 2..3)
#pragma unroll
    for (int mask = 4; mask <= 8; mask <<= 1) {
      l += __shfl_xor(l, mask, 64);
#pragma unroll
      for (int u = 0; u < 8; ++u) acc[u] += __shfl_xor(acc[u], mask, 64);
    }
    float inv = 1.f / (l + 1e-8f);  // degree 0 -> acc 0 -> out 0 (matches ref)
    if (j == 0) {  // 4 r-lanes write 8 dims each = full 32-dim hp slice
      bhalf8 st;
#pragma unroll
      for (int u = 0; u < 8; ++u) st[u] = f2b(acc[u] * inv);
      *(bhalf8*)(&att[nl][hp * 32 + r * 8]) = st;
    }
  }
  __syncthreads();
  // ---- phase 3: out-projection of this block's 8 rows (O = att @ Wo^T + bo) ----
  int w = t >> 6;               // wave 0: cols 0..63, wave 1: cols 64..127
  int plane = t & 63;
  int rr = plane & 15;
  int pg = plane >> 4;
  const short* Wo = Wb + 3 * 16384;
  floatx4 oacc[4];
#pragma unroll
  for (int ntl = 0; ntl < 4; ++ntl) oacc[ntl] = (floatx4){0.f, 0.f, 0.f, 0.f};
#pragma unroll
  for (int kt = 0; kt < 4; ++kt) {
    bhalf8 a;
    if (rr < 8 && node0 + rr < NN) {
      a = *(const bhalf8*)(&att[rr][kt * 32 + pg * 8]);
    } else {
      a = (bhalf8){0, 0, 0, 0, 0, 0, 0, 0};
    }
#pragma unroll
    for (int ntl = 0; ntl < 4; ++ntl) {
      int nt = w * 4 + ntl;
      bhalf8 bb = *(const bhalf8*)(Wo + (nt * 16 + rr) * HID + kt * 32 + pg * 8);
      oacc[ntl] = __builtin_amdgcn_mfma_f32_16x16x32_bf16(a, bb, oacc[ntl], 0, 0, 0);
    }
  }
#pragma unroll
  for (int ntl = 0; ntl < 4; ++ntl) {
    int col = (w * 4 + ntl) * 16 + rr;
    float bias = bo[col];
#pragma unroll
    for (int ii = 0; ii < 4; ++ii) {
      int rw = pg * 4 + ii;  // row in 16-row tile; valid rows are 0..7
      if (rw < 8 && node0 + rw < NN) {
        O[(size_t)(node0 + rw) * HID + col] = oacc[ntl][ii] + bias;
      }
    }
  }
}

// ============================ launch ============================
extern "C" void kernel_launch(void* const* d_in, const int* in_sizes, int n_in,
                              void* d_out, int out_size, void* d_ws,
                              size_t ws_size, hipStream_t stream) {
  const float* q = (const float*)d_in[0];
  const float* k = (const float*)d_in[1];
  const float* v = (const float*)d_in[2];
  const int* ei = (const int*)d_in[3];
  const float* Wq = (const float*)d_in[4];
  const float* bq = (const float*)d_in[5];
  const float* Wk = (const float*)d_in[6];
  const float* bk = (const float*)d_in[7];
  const float* Wv = (const float*)d_in[8];
  const float* bv = (const float*)d_in[9];
  const float* Wo = (const float*)d_in[10];
  const float* bo = (const float*)d_in[11];
  const int* src = ei;
  const int* dst = ei + NE;

  // workspace layout (16B-aligned sections)
  int* tmp = (int*)d_ws;                    // NE ints (packed src<<7|bin)
  int* cnt1 = tmp + NE;                     // 24704
  int* boff = cnt1 + 24704;                 // 160
  short* Wb = (short*)(boff + 160);         // 4*16384 bf16
  short* Qh = Wb + 4 * 16384;               // [4][NN][32] bf16
  short* KVh = Qh + NN * HID;               // [4][NN][64] bf16 (K|V packed)
  float* O = (float*)d_out;

  k_hist_wconv<<<NBLK1 + 64, 256, 0, stream>>>(dst, cnt1, Wq, Wk, Wv, Wo, Wb);
  k_scan_proj<<<1 + 3 * PCHUNK, 1024, 0, stream>>>(cnt1, boff, q, k, v, Wb, bq,
                                                   bk, bv, Qh, KVh);
  k_p1scat<<<NBLK1, 256, 0, stream>>>(src, dst, cnt1, tmp);
  k_edge<<<NBUCK * 16, 128, 0, stream>>>(tmp, boff, Qh, KVh, Wb, bo, O);
}